// Round 1
// baseline (227.864 us; speedup 1.0000x reference)
//
#include <hip/hip_runtime.h>
#include <hip/hip_bf16.h>
#include <math.h>

// B = 8192 samples, NS = 4 samples per block.
#define BATCH 8192
#define NS 4

// -----------------------------------------------------------------------------
// Fused per-sample CNN: conv1(1->8,3x3,SAME)+ReLU+pool2 -> conv2(8->16)+ReLU+
// pool2 -> FC1(784->64)+ReLU -> FC2(64->4) -> logits[B,4].
// One block handles NS=4 consecutive samples; everything stays in LDS.
// -----------------------------------------------------------------------------
__global__ __launch_bounds__(256) void fused_cnn(
    const float* __restrict__ x,      // [B,1,28,28]
    const float* __restrict__ c1w,    // [8,1,3,3]
    const float* __restrict__ c1b,    // [8]
    const float* __restrict__ c2w,    // [16,8,3,3]
    const float* __restrict__ c2b,    // [16]
    const float* __restrict__ f1w,    // [64,784]
    const float* __restrict__ f1b,    // [64]
    const float* __restrict__ f2w,    // [4,64]
    const float* __restrict__ f2b,    // [4]
    float* __restrict__ logits)       // [B,4]
{
    const int tid  = threadIdx.x;
    const int wid  = tid >> 6;    // wave 0..3
    const int lane = tid & 63;
    const int b0   = blockIdx.x * NS;

    __shared__ __align__(16) float sxp[30 * 30];      // zero-padded 28x28 image
    __shared__ __align__(16) float sh1p[8 * 16 * 18]; // zero-padded h1, row stride 18
    __shared__ __align__(16) float sw2[16 * 72];      // conv2 weights
    __shared__ __align__(16) float sfeat[NS][784];    // flattened feats per sample
    __shared__ __align__(16) float sh[NS][64];        // FC1 activations

    // conv2 weights -> LDS (reads are wave-uniform broadcast later)
    for (int i = tid; i < 16 * 72; i += 256) sw2[i] = c2w[i];
    // zero whole padded h1 once (interior rewritten per sample, border stays 0)
    for (int i = tid; i < 8 * 16 * 18; i += 256) sh1p[i] = 0.f;

    // conv1 weights: wave w owns output channels {2w, 2w+1}, keep in registers
    float w1a[9], w1b[9];
#pragma unroll
    for (int k = 0; k < 9; ++k) {
        w1a[k] = c1w[(2 * wid) * 9 + k];
        w1b[k] = c1w[(2 * wid + 1) * 9 + k];
    }
    const float b1a = c1b[2 * wid];
    const float b1b = c1b[2 * wid + 1];
    // conv2 biases: wave w owns output channels {4w..4w+3}
    float b2[4];
#pragma unroll
    for (int o = 0; o < 4; ++o) b2[o] = c2b[4 * wid + o];

    __syncthreads();

    for (int s = 0; s < NS; ++s) {
        // ---- stage 0: load zero-padded image --------------------------------
        const float* xb = x + (size_t)(b0 + s) * 784;
        for (int i = tid; i < 900; i += 256) {
            int r = i / 30, c = i - r * 30;
            float v = 0.f;
            if (r >= 1 && r <= 28 && c >= 1 && c <= 28) v = xb[(r - 1) * 28 + (c - 1)];
            sxp[i] = v;
        }
        __syncthreads();

        // ---- stage 1: conv1 + bias + pool + relu ---------------------------
        // pooled output (py,px) in 14x14; patch rows 2py..2py+3, cols 2px..2px+3
        for (int pix = lane; pix < 196; pix += 64) {
            int py = pix / 14, px = pix - py * 14;
            int r0 = 2 * py, c0 = 2 * px;
            float patch[4][4];
#pragma unroll
            for (int r = 0; r < 4; ++r) {
                float2 u = *(const float2*)&sxp[(r0 + r) * 30 + c0];
                float2 v = *(const float2*)&sxp[(r0 + r) * 30 + c0 + 2];
                patch[r][0] = u.x; patch[r][1] = u.y;
                patch[r][2] = v.x; patch[r][3] = v.y;
            }
            float m0 = -1e30f, m1 = -1e30f;
#pragma unroll
            for (int dy = 0; dy < 2; ++dy)
#pragma unroll
            for (int dx = 0; dx < 2; ++dx) {
                float a0 = b1a, a1 = b1b;
#pragma unroll
                for (int ky = 0; ky < 3; ++ky)
#pragma unroll
                for (int kx = 0; kx < 3; ++kx) {
                    float pv = patch[dy + ky][dx + kx];
                    a0 += pv * w1a[ky * 3 + kx];
                    a1 += pv * w1b[ky * 3 + kx];
                }
                m0 = fmaxf(m0, a0);
                m1 = fmaxf(m1, a1);
            }
            sh1p[(2 * wid) * 288 + (py + 1) * 18 + (px + 1)]     = fmaxf(m0, 0.f);
            sh1p[(2 * wid + 1) * 288 + (py + 1) * 18 + (px + 1)] = fmaxf(m1, 0.f);
        }
        __syncthreads();

        // ---- stage 2: conv2 + bias + pool + relu ---------------------------
        // lane -> pooled pixel in 7x7 (lanes 49..63 idle); wave -> 4 out channels
        if (lane < 49) {
            int py = lane / 7, px = lane - py * 7;
            int r0 = 2 * py, c0 = 2 * px;   // padded coords (interior at +1)
            float acc[4][4];
#pragma unroll
            for (int o = 0; o < 4; ++o)
#pragma unroll
                for (int p = 0; p < 4; ++p) acc[o][p] = b2[o];

#pragma unroll
            for (int ic = 0; ic < 8; ++ic) {
                float patch[4][4];
#pragma unroll
                for (int r = 0; r < 4; ++r) {
                    const float* base = &sh1p[ic * 288 + (r0 + r) * 18 + c0];
                    float2 u = *(const float2*)base;
                    float2 v = *(const float2*)(base + 2);
                    patch[r][0] = u.x; patch[r][1] = u.y;
                    patch[r][2] = v.x; patch[r][3] = v.y;
                }
#pragma unroll
                for (int o = 0; o < 4; ++o) {
                    const float* wo = &sw2[(4 * wid + o) * 72 + ic * 9];
#pragma unroll
                    for (int dy = 0; dy < 2; ++dy)
#pragma unroll
                    for (int dx = 0; dx < 2; ++dx) {
                        float a = 0.f;
#pragma unroll
                        for (int ky = 0; ky < 3; ++ky)
#pragma unroll
                        for (int kx = 0; kx < 3; ++kx)
                            a += patch[dy + ky][dx + kx] * wo[ky * 3 + kx];
                        acc[o][dy * 2 + dx] += a;
                    }
                }
            }
#pragma unroll
            for (int o = 0; o < 4; ++o) {
                float m = fmaxf(fmaxf(acc[o][0], acc[o][1]), fmaxf(acc[o][2], acc[o][3]));
                sfeat[s][(4 * wid + o) * 49 + lane] = fmaxf(m, 0.f);
            }
        }
        __syncthreads();
    }

    // ---- stage 3: FC1 (784 -> 64) + ReLU, 4 samples at once ----------------
    {
        const int o = tid >> 2;   // output 0..63
        const int p = tid & 3;    // k-partition 0..3 (196 each)
        const float4* __restrict__ w4 = (const float4*)(f1w + o * 784 + p * 196);
        const float4* f0 = (const float4*)&sfeat[0][p * 196];
        const float4* f1 = (const float4*)&sfeat[1][p * 196];
        const float4* f2 = (const float4*)&sfeat[2][p * 196];
        const float4* f3 = (const float4*)&sfeat[3][p * 196];
        float a0 = 0.f, a1 = 0.f, a2 = 0.f, a3 = 0.f;
        for (int i = 0; i < 49; ++i) {
            float4 w = w4[i];
            float4 v0 = f0[i]; a0 += w.x * v0.x + w.y * v0.y + w.z * v0.z + w.w * v0.w;
            float4 v1 = f1[i]; a1 += w.x * v1.x + w.y * v1.y + w.z * v1.z + w.w * v1.w;
            float4 v2 = f2[i]; a2 += w.x * v2.x + w.y * v2.y + w.z * v2.z + w.w * v2.w;
            float4 v3 = f3[i]; a3 += w.x * v3.x + w.y * v3.y + w.z * v3.z + w.w * v3.w;
        }
        // reduce over the 4 k-partitions (lanes 4o..4o+3 are consecutive)
        a0 += __shfl_xor(a0, 1); a0 += __shfl_xor(a0, 2);
        a1 += __shfl_xor(a1, 1); a1 += __shfl_xor(a1, 2);
        a2 += __shfl_xor(a2, 1); a2 += __shfl_xor(a2, 2);
        a3 += __shfl_xor(a3, 1); a3 += __shfl_xor(a3, 2);
        if (p == 0) {
            const float bb = f1b[o];
            sh[0][o] = fmaxf(a0 + bb, 0.f);
            sh[1][o] = fmaxf(a1 + bb, 0.f);
            sh[2][o] = fmaxf(a2 + bb, 0.f);
            sh[3][o] = fmaxf(a3 + bb, 0.f);
        }
    }
    __syncthreads();

    // ---- stage 4: FC2 (64 -> 4): wave w computes logit channel w -----------
    {
        const int o = wid, k = lane;
        const float wv = f2w[o * 64 + k];
        float a0 = sh[0][k] * wv;
        float a1 = sh[1][k] * wv;
        float a2 = sh[2][k] * wv;
        float a3 = sh[3][k] * wv;
#pragma unroll
        for (int sft = 32; sft >= 1; sft >>= 1) {
            a0 += __shfl_xor(a0, sft);
            a1 += __shfl_xor(a1, sft);
            a2 += __shfl_xor(a2, sft);
            a3 += __shfl_xor(a3, sft);
        }
        if (k == 0) {
            const float bb = f2b[o];
            logits[(size_t)(b0 + 0) * 4 + o] = a0 + bb;
            logits[(size_t)(b0 + 1) * 4 + o] = a1 + bb;
            logits[(size_t)(b0 + 2) * 4 + o] = a2 + bb;
            logits[(size_t)(b0 + 3) * 4 + o] = a3 + bb;
        }
    }
}

// -----------------------------------------------------------------------------
// Stats reduction: per-block partial sums of logits and logits^2 per channel.
// 32 blocks x 256 threads; block i handles samples [i*256, (i+1)*256).
// -----------------------------------------------------------------------------
__global__ __launch_bounds__(256) void reduce_stats(
    const float* __restrict__ logits, float* __restrict__ partials /* [32][8] */)
{
    const int tid = threadIdx.x;
    const int i = blockIdx.x * 256 + tid;      // sample id, 0..8191
    float4 v = ((const float4*)logits)[i];
    float t[8] = { v.x, v.y, v.z, v.w, v.x * v.x, v.y * v.y, v.z * v.z, v.w * v.w };
#pragma unroll
    for (int sft = 32; sft >= 1; sft >>= 1) {
#pragma unroll
        for (int j = 0; j < 8; ++j) t[j] += __shfl_xor(t[j], sft);
    }
    __shared__ float part[4][8];
    if ((tid & 63) == 0) {
#pragma unroll
        for (int j = 0; j < 8; ++j) part[tid >> 6][j] = t[j];
    }
    __syncthreads();
    if (tid < 8) {
        float s = part[0][tid] + part[1][tid] + part[2][tid] + part[3][tid];
        partials[blockIdx.x * 8 + tid] = s;
    }
}

// -----------------------------------------------------------------------------
// Finalize: sum partials -> BN mean/inv-std; simulate the 4-qubit circuit once
// (feature-map RZ on |0000> is a pure global phase -> q is batch-constant);
// emit per-channel scale/shift with the quantum expectation folded in.
// -----------------------------------------------------------------------------
__global__ void finalize_params(
    const float* __restrict__ var,      // [12]
    const float* __restrict__ gamma,    // [4]
    const float* __restrict__ beta,     // [4]
    const float* __restrict__ partials, // [32][8]
    float* __restrict__ params)         // out: scale[4], shift[4]
{
    if (threadIdx.x != 0 || blockIdx.x != 0) return;

    // ---- batch stats ----
    float sums[8];
#pragma unroll
    for (int j = 0; j < 8; ++j) sums[j] = 0.f;
    for (int blk = 0; blk < 32; ++blk)
#pragma unroll
        for (int j = 0; j < 8; ++j) sums[j] += partials[blk * 8 + j];

    // ---- 4-qubit statevector sim (ansatz + CNOT chain only) ----
    float pr[16], pi[16];
#pragma unroll
    for (int i = 0; i < 16; ++i) { pr[i] = 0.f; pi[i] = 0.f; }
    pr[0] = 1.f;
    for (int q = 0; q < 4; ++q) {
        float a  = var[3 * q], b_ = var[3 * q + 1], c = var[3 * q + 2];
        float ca = cosf(0.5f * a),  sa = sinf(0.5f * a);
        float cb = cosf(0.5f * b_), sb = sinf(0.5f * b_);
        float cc = cosf(0.5f * c),  sc = sinf(0.5f * c);
        // M = RY * RX
        float m00r = cb * ca, m00i =  sb * sa;
        float m01r = -sb * ca, m01i = -cb * sa;
        float m10r =  sb * ca, m10i = -cb * sa;
        float m11r =  cb * ca, m11i = -sb * sa;
        // U = RZ * M : row0 *= (cc - i sc), row1 *= (cc + i sc)
        float u00r = cc * m00r + sc * m00i, u00i = cc * m00i - sc * m00r;
        float u01r = cc * m01r + sc * m01i, u01i = cc * m01i - sc * m01r;
        float u10r = cc * m10r - sc * m10i, u10i = cc * m10i + sc * m10r;
        float u11r = cc * m11r - sc * m11i, u11i = cc * m11i + sc * m11r;
        int stq = 1 << (3 - q);   // qubit q stride in flattened [2,2,2,2]
        for (int i = 0; i < 16; ++i) {
            if (i & stq) continue;
            int j = i | stq;
            float xr = pr[i], xi = pi[i], yr = pr[j], yi = pi[j];
            pr[i] = u00r * xr - u00i * xi + u01r * yr - u01i * yi;
            pi[i] = u00r * xi + u00i * xr + u01r * yi + u01i * yr;
            pr[j] = u10r * xr - u10i * xi + u11r * yr - u11i * yi;
            pi[j] = u10r * xi + u10i * xr + u11r * yi + u11i * yr;
        }
    }
    // CNOT chain: control q, target q+1
    for (int c = 0; c < 3; ++c) {
        int scm = 1 << (3 - c), stm = 1 << (2 - c);
        for (int i = 0; i < 16; ++i) {
            if ((i & scm) && !(i & stm)) {
                int j = i | stm;
                float tr = pr[i], ti = pi[i];
                pr[i] = pr[j]; pi[i] = pi[j];
                pr[j] = tr;    pi[j] = ti;
            }
        }
    }
    float p[16];
#pragma unroll
    for (int i = 0; i < 16; ++i) p[i] = pr[i] * pr[i] + pi[i] * pi[i];
    float e[4];
    for (int k = 0; k < 4; ++k) {
        float s = 0.f;
        for (int i = 0; i < 16; ++i)
            s += ((i >> (3 - k)) & 1) ? -p[i] : p[i];
        e[k] = s;
    }

    // ---- fold BN + quantum constant into per-channel affine ----
    const float invB = 1.0f / (float)BATCH;
    for (int j = 0; j < 4; ++j) {
        float mu   = sums[j] * invB;
        float vr   = sums[4 + j] * invB - mu * mu;
        float istd = 1.0f / sqrtf(vr + 1e-5f);
        float scale = gamma[j] * istd;
        float qv = e[3 - j];   // Pauli label ordering reverses qubit index
        params[j]     = scale;
        params[4 + j] = beta[j] - mu * scale + qv;
    }
}

// -----------------------------------------------------------------------------
// out[b][j] = logits[b][j] * scale[j] + shift[j]
// -----------------------------------------------------------------------------
__global__ __launch_bounds__(256) void apply_bn(
    const float* __restrict__ logits, const float* __restrict__ params,
    float* __restrict__ out)
{
    const int i = blockIdx.x * 256 + threadIdx.x;   // sample id
    float4 v = ((const float4*)logits)[i];
    float4 r;
    r.x = v.x * params[0] + params[4];
    r.y = v.y * params[1] + params[5];
    r.z = v.z * params[2] + params[6];
    r.w = v.w * params[3] + params[7];
    ((float4*)out)[i] = r;
}

extern "C" void kernel_launch(void* const* d_in, const int* in_sizes, int n_in,
                              void* d_out, int out_size, void* d_ws, size_t ws_size,
                              hipStream_t stream) {
    (void)in_sizes; (void)n_in; (void)out_size; (void)ws_size;
    const float* x   = (const float*)d_in[0];
    const float* c1w = (const float*)d_in[1];
    const float* c1b = (const float*)d_in[2];
    const float* c2w = (const float*)d_in[3];
    const float* c2b = (const float*)d_in[4];
    const float* f1w = (const float*)d_in[5];
    const float* f1b = (const float*)d_in[6];
    const float* f2w = (const float*)d_in[7];
    const float* f2b = (const float*)d_in[8];
    const float* gma = (const float*)d_in[9];
    const float* bta = (const float*)d_in[10];
    const float* var = (const float*)d_in[11];
    float* out = (float*)d_out;

    float* logits   = (float*)d_ws;          // 32768 floats
    float* partials = logits + 32768;        // 256 floats
    float* params   = partials + 256;        // 8 floats

    fused_cnn<<<BATCH / NS, 256, 0, stream>>>(x, c1w, c1b, c2w, c2b,
                                              f1w, f1b, f2w, f2b, logits);
    reduce_stats<<<32, 256, 0, stream>>>(logits, partials);
    finalize_params<<<1, 64, 0, stream>>>(var, gma, bta, partials, params);
    apply_bn<<<32, 256, 0, stream>>>(logits, params, out);
}

// Round 2
// 178.159 us; speedup vs baseline: 1.2790x; 1.2790x over previous
//
#include <hip/hip_runtime.h>
#include <hip/hip_fp16.h>
#include <math.h>
#include <stdint.h>

#define BATCH 8192
#define NS 4

typedef _Float16 half_t;
typedef _Float16 h2_t __attribute__((ext_vector_type(2)));

// v_dot2_f32_f16: (a.lo*b.lo + a.hi*b.hi) + c, fp32 accumulate
__device__ __forceinline__ float fdot2(uint32_t a, uint32_t b, float c) {
#if __has_builtin(__builtin_amdgcn_fdot2)
    return __builtin_amdgcn_fdot2(__builtin_bit_cast(h2_t, a),
                                  __builtin_bit_cast(h2_t, b), c, false);
#else
    h2_t ha = __builtin_bit_cast(h2_t, a), hb = __builtin_bit_cast(h2_t, b);
    return c + (float)ha[0] * (float)hb[0] + (float)ha[1] * (float)hb[1];
#endif
}

__device__ __forceinline__ uint32_t pack2(float a, float b) {
#if __has_builtin(__builtin_amdgcn_cvt_pkrtz)
    return __builtin_bit_cast(uint32_t, __builtin_amdgcn_cvt_pkrtz(a, b));
#else
    h2_t h; h[0] = (half_t)a; h[1] = (half_t)b;
    return __builtin_bit_cast(uint32_t, h);
#endif
}

// force a wave-uniform value into an SGPR
__device__ __forceinline__ float rfl_f(float v) {
    return __builtin_bit_cast(float,
        (uint32_t)__builtin_amdgcn_readfirstlane((int)__builtin_bit_cast(uint32_t, v)));
}
__device__ __forceinline__ uint32_t rfl_u(uint32_t v) {
    return (uint32_t)__builtin_amdgcn_readfirstlane((int)v);
}

// -----------------------------------------------------------------------------
// Prologue: pack FC1 weights to f16 (reordered + padded for clean b128 reads)
// and conv2 weights to f16x2 pairs (4-ic interleave groups).
// w1p32 layout: [o=64][chunk=4][100] u32, each u32 = halves (f'=2k, 2k+1) of
//   chunk-local feature index; f' = pix*16 + oc, orig = oc*49 + pix. Pads = 0.
// w2p layout: [ipq=2][oc=16][tap=9][h=2] u32; h selects ic pair within group:
//   u32 = pack(c2w[oc][4*ipq+2h][tap], c2w[oc][4*ipq+2h+1][tap])
// -----------------------------------------------------------------------------
__global__ __launch_bounds__(256) void pack_weights(
    const float* __restrict__ f1w, const float* __restrict__ c2w,
    uint32_t* __restrict__ w1p32, uint32_t* __restrict__ w2p)
{
    int idx = blockIdx.x * 256 + threadIdx.x;
    if (idx < 64 * 400) {
        int o = idx / 400, k2 = idx - o * 400;
        int chunk = k2 / 100, pos2 = k2 - chunk * 100;
        float v0 = 0.f, v1 = 0.f;
        int pp0 = 2 * pos2;
        if (pp0 < 196) {
            int fp = chunk * 196 + pp0;
            v0 = f1w[o * 784 + (fp & 15) * 49 + (fp >> 4)];
        }
        int pp1 = 2 * pos2 + 1;
        if (pp1 < 196) {
            int fp = chunk * 196 + pp1;
            v1 = f1w[o * 784 + (fp & 15) * 49 + (fp >> 4)];
        }
        w1p32[idx] = pack2(v0, v1);
    } else if (idx < 64 * 400 + 576) {
        int j = idx - 64 * 400;
        int ipq = j / 288, r = j - ipq * 288;
        int oc = r / 18, r2 = r - oc * 18;
        int t = r2 >> 1, h = r2 & 1;
        int ic = ipq * 4 + 2 * h;
        w2p[j] = pack2(c2w[(oc * 8 + ic) * 9 + t],
                       c2w[(oc * 8 + ic + 1) * 9 + t]);
    }
}

// -----------------------------------------------------------------------------
// Fused CNN: conv1+pool -> conv2+pool (f16 dot2, weights in SGPR) -> FC1 (f16
// dot2) -> FC2 -> logits[B,4]. One block = 4 samples, 4 waves.
// -----------------------------------------------------------------------------
__global__ __launch_bounds__(256) void fused_cnn(
    const float* __restrict__ x,      // [B,1,28,28]
    const float* __restrict__ c1w,    // [8,9]
    const float* __restrict__ c1b,    // [8]
    const float* __restrict__ c2b,    // [16]
    const uint32_t* __restrict__ w2p, // packed conv2 weights
    const uint32_t* __restrict__ w1p32,// packed fc1 weights
    const float* __restrict__ f1b,    // [64]
    const float* __restrict__ f2w,    // [4,64]
    const float* __restrict__ f2b,    // [4]
    float* __restrict__ logits)       // [B,4]
{
    const int tid  = threadIdx.x;
    const int lane = tid & 63;
    const int b0   = blockIdx.x * NS;
    const int uwid = __builtin_amdgcn_readfirstlane(tid >> 6);

    // h1: [s][ipq=2][row=16][pos=18] of uint2 (= 4 interleaved f16 channels)
    __shared__ __align__(16) uint2    h1[NS * 2 * 16 * 18];   // 18432 B
    __shared__ __align__(16) uint32_t sfeatu[NS][400];        // f16x2 feats, 6400 B
    __shared__ __align__(16) float    sh[NS][64];             // 1024 B

    // ---- zero-init h1 (borders must be 0) and sfeat (pads must be 0) --------
    {
        uint32_t* h1u = (uint32_t*)h1;
        for (int i = tid; i < NS * 2 * 16 * 18 * 2; i += 256) h1u[i] = 0;
        uint32_t* sf = (uint32_t*)sfeatu;
        for (int i = tid; i < NS * 400; i += 256) sf[i] = 0;
    }

    // conv1 weights/biases -> SGPRs (wave-uniform)
    float ws1[72], bs1[8];
#pragma unroll
    for (int t = 0; t < 72; ++t) ws1[t] = rfl_f(c1w[t]);
#pragma unroll
    for (int o = 0; o < 8; ++o) bs1[o] = rfl_f(c1b[o]);

    __syncthreads();

    // ---- stage 1: conv1 + pool + relu, image read straight from global -----
#pragma unroll 1
    for (int pass = 0; pass < 4; ++pass) {
        int item = pass * 256 + tid;          // (s, pooled pix) over 4*196
        if (item < NS * 196) {
            int s = item / 196;
            int pix = item - s * 196;
            int py = pix / 14, px = pix - 14 * py;
            const float* xb = x + (size_t)(b0 + s) * 784;
            float patch[16];
#pragma unroll
            for (int rr = 0; rr < 4; ++rr) {
                int r = 2 * py - 1 + rr;
#pragma unroll
                for (int cc = 0; cc < 4; ++cc) {
                    int c = 2 * px - 1 + cc;
                    bool ok = ((unsigned)r < 28u) && ((unsigned)c < 28u);
                    patch[rr * 4 + cc] = ok ? xb[r * 28 + c] : 0.f;
                }
            }
            float m[8];
#pragma unroll
            for (int o = 0; o < 8; ++o) {
                float a00 = bs1[o], a01 = bs1[o], a10 = bs1[o], a11 = bs1[o];
#pragma unroll
                for (int ky = 0; ky < 3; ++ky) {
#pragma unroll
                    for (int kx = 0; kx < 3; ++kx) {
                        float w = ws1[o * 9 + ky * 3 + kx];
                        a00 += patch[ky * 4 + kx]           * w;
                        a01 += patch[ky * 4 + kx + 1]       * w;
                        a10 += patch[(ky + 1) * 4 + kx]     * w;
                        a11 += patch[(ky + 1) * 4 + kx + 1] * w;
                    }
                }
                m[o] = fmaxf(fmaxf(fmaxf(a00, a01), fmaxf(a10, a11)), 0.f);
            }
            h1[((s * 2 + 0) * 16 + (py + 1)) * 18 + (px + 1)] =
                make_uint2(pack2(m[0], m[1]), pack2(m[2], m[3]));
            h1[((s * 2 + 1) * 16 + (py + 1)) * 18 + (px + 1)] =
                make_uint2(pack2(m[4], m[5]), pack2(m[6], m[7]));
        }
    }
    __syncthreads();

    // ---- stage 2: conv2 + pool + relu via f16 dot2, weights in SGPR --------
    {
        int p7 = lane / 7, q7 = lane - 7 * p7;     // pooled (py,px), lane<49
        float b2[4];
#pragma unroll
        for (int o = 0; o < 4; ++o) b2[o] = rfl_f(c2b[uwid * 4 + o]);
        float acc[NS][4][4];
#pragma unroll
        for (int s = 0; s < NS; ++s)
#pragma unroll
            for (int o = 0; o < 4; ++o)
#pragma unroll
                for (int q = 0; q < 4; ++q) acc[s][o][q] = b2[o];

#pragma unroll 1
        for (int ipq = 0; ipq < 2; ++ipq) {
            uint32_t wv[72];
#pragma unroll
            for (int t = 0; t < 72; ++t)
                wv[t] = rfl_u(w2p[ipq * 288 + uwid * 72 + t]);
            if (lane < 49) {
#pragma unroll
                for (int s = 0; s < NS; ++s) {
                    const uint2* hb = &h1[((s * 2 + ipq) * 16 + 2 * p7) * 18 + 2 * q7];
                    uint2 patch[16];
#pragma unroll
                    for (int r = 0; r < 4; ++r)
#pragma unroll
                        for (int c = 0; c < 4; ++c)
                            patch[r * 4 + c] = hb[r * 18 + c];
#pragma unroll
                    for (int o = 0; o < 4; ++o) {
#pragma unroll
                        for (int dy = 0; dy < 2; ++dy) {
#pragma unroll
                            for (int dx = 0; dx < 2; ++dx) {
                                float a = acc[s][o][dy * 2 + dx];
#pragma unroll
                                for (int ky = 0; ky < 3; ++ky) {
#pragma unroll
                                    for (int kx = 0; kx < 3; ++kx) {
                                        int t = ky * 3 + kx;
                                        uint2 pv = patch[(dy + ky) * 4 + (dx + kx)];
                                        a = fdot2(pv.x, wv[o * 18 + t * 2],     a);
                                        a = fdot2(pv.y, wv[o * 18 + t * 2 + 1], a);
                                    }
                                }
                                acc[s][o][dy * 2 + dx] = a;
                            }
                        }
                    }
                }
            }
        }
        // pool + relu + pack to f16 feats (reordered f' = pix*16 + oc)
        if (lane < 49) {
#pragma unroll
            for (int s = 0; s < NS; ++s) {
#pragma unroll
                for (int j = 0; j < 2; ++j) {
                    float f0 = fmaxf(fmaxf(fmaxf(acc[s][2*j][0], acc[s][2*j][1]),
                                           fmaxf(acc[s][2*j][2], acc[s][2*j][3])), 0.f);
                    float f1 = fmaxf(fmaxf(fmaxf(acc[s][2*j+1][0], acc[s][2*j+1][1]),
                                           fmaxf(acc[s][2*j+1][2], acc[s][2*j+1][3])), 0.f);
                    int fp0 = lane * 16 + uwid * 4 + 2 * j;   // even
                    int chunk = fp0 / 196;
                    int pos = fp0 - chunk * 196;
                    sfeatu[s][chunk * 100 + (pos >> 1)] = pack2(f0, f1);
                }
            }
        }
    }
    __syncthreads();

    // ---- stage 3: FC1 (784->64) via f16 dot2, 4 samples at once ------------
    {
        const int o = tid >> 2, p = tid & 3;
        float a0 = 0.f, a1 = 0.f, a2 = 0.f, a3 = 0.f;
        const uint4* wq = (const uint4*)(w1p32 + o * 400 + p * 100);
        const uint4* F0 = (const uint4*)&sfeatu[0][p * 100];
        const uint4* F1 = (const uint4*)&sfeatu[1][p * 100];
        const uint4* F2 = (const uint4*)&sfeatu[2][p * 100];
        const uint4* F3 = (const uint4*)&sfeatu[3][p * 100];
#pragma unroll 1
        for (int i = 0; i < 25; ++i) {
            uint4 w = wq[i];
            uint4 f0 = F0[i];
            a0 = fdot2(w.x, f0.x, a0); a0 = fdot2(w.y, f0.y, a0);
            a0 = fdot2(w.z, f0.z, a0); a0 = fdot2(w.w, f0.w, a0);
            uint4 f1 = F1[i];
            a1 = fdot2(w.x, f1.x, a1); a1 = fdot2(w.y, f1.y, a1);
            a1 = fdot2(w.z, f1.z, a1); a1 = fdot2(w.w, f1.w, a1);
            uint4 f2 = F2[i];
            a2 = fdot2(w.x, f2.x, a2); a2 = fdot2(w.y, f2.y, a2);
            a2 = fdot2(w.z, f2.z, a2); a2 = fdot2(w.w, f2.w, a2);
            uint4 f3 = F3[i];
            a3 = fdot2(w.x, f3.x, a3); a3 = fdot2(w.y, f3.y, a3);
            a3 = fdot2(w.z, f3.z, a3); a3 = fdot2(w.w, f3.w, a3);
        }
        a0 += __shfl_xor(a0, 1); a0 += __shfl_xor(a0, 2);
        a1 += __shfl_xor(a1, 1); a1 += __shfl_xor(a1, 2);
        a2 += __shfl_xor(a2, 1); a2 += __shfl_xor(a2, 2);
        a3 += __shfl_xor(a3, 1); a3 += __shfl_xor(a3, 2);
        if (p == 0) {
            const float bb = f1b[o];
            sh[0][o] = fmaxf(a0 + bb, 0.f);
            sh[1][o] = fmaxf(a1 + bb, 0.f);
            sh[2][o] = fmaxf(a2 + bb, 0.f);
            sh[3][o] = fmaxf(a3 + bb, 0.f);
        }
    }
    __syncthreads();

    // ---- stage 4: FC2 (64->4): wave computes its logit channel -------------
    {
        const int o = uwid, k = lane;
        const float wv = f2w[o * 64 + k];
        float a0 = sh[0][k] * wv;
        float a1 = sh[1][k] * wv;
        float a2 = sh[2][k] * wv;
        float a3 = sh[3][k] * wv;
#pragma unroll
        for (int sft = 32; sft >= 1; sft >>= 1) {
            a0 += __shfl_xor(a0, sft);
            a1 += __shfl_xor(a1, sft);
            a2 += __shfl_xor(a2, sft);
            a3 += __shfl_xor(a3, sft);
        }
        if (k == 0) {
            const float bb = f2b[o];
            logits[(size_t)(b0 + 0) * 4 + o] = a0 + bb;
            logits[(size_t)(b0 + 1) * 4 + o] = a1 + bb;
            logits[(size_t)(b0 + 2) * 4 + o] = a2 + bb;
            logits[(size_t)(b0 + 3) * 4 + o] = a3 + bb;
        }
    }
}

// -----------------------------------------------------------------------------
// Tail: each of 32 blocks redundantly reduces all logits -> BN stats; thread 0
// runs the (batch-constant) 4-qubit sim; block applies affine to its slice.
// -----------------------------------------------------------------------------
__global__ __launch_bounds__(256) void stats_apply(
    const float* __restrict__ logits, const float* __restrict__ var,
    const float* __restrict__ gamma, const float* __restrict__ beta,
    float* __restrict__ out)
{
    const int tid = threadIdx.x;
    const float4* l4 = (const float4*)logits;

    float t[8] = {0, 0, 0, 0, 0, 0, 0, 0};
#pragma unroll 4
    for (int i = 0; i < 32; ++i) {
        float4 v = l4[tid + 256 * i];
        t[0] += v.x; t[1] += v.y; t[2] += v.z; t[3] += v.w;
        t[4] += v.x * v.x; t[5] += v.y * v.y; t[6] += v.z * v.z; t[7] += v.w * v.w;
    }
#pragma unroll
    for (int sft = 32; sft >= 1; sft >>= 1)
#pragma unroll
        for (int j = 0; j < 8; ++j) t[j] += __shfl_xor(t[j], sft);

    __shared__ float part[4][8];
    __shared__ float prm[8];
    if ((tid & 63) == 0) {
#pragma unroll
        for (int j = 0; j < 8; ++j) part[tid >> 6][j] = t[j];
    }
    __syncthreads();

    if (tid == 0) {
        float sums[8];
#pragma unroll
        for (int j = 0; j < 8; ++j)
            sums[j] = part[0][j] + part[1][j] + part[2][j] + part[3][j];

        // 4-qubit statevector sim (ansatz + CNOT chain; feature-map RZ on
        // |0000> is a global phase -> batch-constant expectations)
        float pr[16], pi[16];
#pragma unroll
        for (int i = 0; i < 16; ++i) { pr[i] = 0.f; pi[i] = 0.f; }
        pr[0] = 1.f;
        for (int q = 0; q < 4; ++q) {
            float a  = var[3 * q], b_ = var[3 * q + 1], c = var[3 * q + 2];
            float ca = cosf(0.5f * a),  sa = sinf(0.5f * a);
            float cb = cosf(0.5f * b_), sb = sinf(0.5f * b_);
            float cc = cosf(0.5f * c),  sc = sinf(0.5f * c);
            float m00r = cb * ca, m00i =  sb * sa;
            float m01r = -sb * ca, m01i = -cb * sa;
            float m10r =  sb * ca, m10i = -cb * sa;
            float m11r =  cb * ca, m11i = -sb * sa;
            float u00r = cc * m00r + sc * m00i, u00i = cc * m00i - sc * m00r;
            float u01r = cc * m01r + sc * m01i, u01i = cc * m01i - sc * m01r;
            float u10r = cc * m10r - sc * m10i, u10i = cc * m10i + sc * m10r;
            float u11r = cc * m11r - sc * m11i, u11i = cc * m11i + sc * m11r;
            int stq = 1 << (3 - q);
            for (int i = 0; i < 16; ++i) {
                if (i & stq) continue;
                int j = i | stq;
                float xr = pr[i], xi = pi[i], yr = pr[j], yi = pi[j];
                pr[i] = u00r * xr - u00i * xi + u01r * yr - u01i * yi;
                pi[i] = u00r * xi + u00i * xr + u01r * yi + u01i * yr;
                pr[j] = u10r * xr - u10i * xi + u11r * yr - u11i * yi;
                pi[j] = u10r * xi + u10i * xr + u11r * yi + u11i * yr;
            }
        }
        for (int c = 0; c < 3; ++c) {
            int scm = 1 << (3 - c), stm = 1 << (2 - c);
            for (int i = 0; i < 16; ++i) {
                if ((i & scm) && !(i & stm)) {
                    int j = i | stm;
                    float tr = pr[i], ti = pi[i];
                    pr[i] = pr[j]; pi[i] = pi[j];
                    pr[j] = tr;    pi[j] = ti;
                }
            }
        }
        float p[16];
#pragma unroll
        for (int i = 0; i < 16; ++i) p[i] = pr[i] * pr[i] + pi[i] * pi[i];
        float e[4];
        for (int k = 0; k < 4; ++k) {
            float s = 0.f;
            for (int i = 0; i < 16; ++i)
                s += ((i >> (3 - k)) & 1) ? -p[i] : p[i];
            e[k] = s;
        }
        const float invB = 1.0f / (float)BATCH;
        for (int j = 0; j < 4; ++j) {
            float mu   = sums[j] * invB;
            float vr   = sums[4 + j] * invB - mu * mu;
            float istd = 1.0f / sqrtf(vr + 1e-5f);
            float scale = gamma[j] * istd;
            prm[j]     = scale;
            prm[4 + j] = beta[j] - mu * scale + e[3 - j];
        }
    }
    __syncthreads();

    const int smp = blockIdx.x * 256 + tid;
    float4 v = l4[smp];
    float4 r;
    r.x = v.x * prm[0] + prm[4];
    r.y = v.y * prm[1] + prm[5];
    r.z = v.z * prm[2] + prm[6];
    r.w = v.w * prm[3] + prm[7];
    ((float4*)out)[smp] = r;
}

extern "C" void kernel_launch(void* const* d_in, const int* in_sizes, int n_in,
                              void* d_out, int out_size, void* d_ws, size_t ws_size,
                              hipStream_t stream) {
    (void)in_sizes; (void)n_in; (void)out_size; (void)ws_size;
    const float* x   = (const float*)d_in[0];
    const float* c1w = (const float*)d_in[1];
    const float* c1b = (const float*)d_in[2];
    const float* c2w = (const float*)d_in[3];
    const float* c2b = (const float*)d_in[4];
    const float* f1w = (const float*)d_in[5];
    const float* f1b = (const float*)d_in[6];
    const float* f2w = (const float*)d_in[7];
    const float* f2b = (const float*)d_in[8];
    const float* gma = (const float*)d_in[9];
    const float* bta = (const float*)d_in[10];
    const float* var = (const float*)d_in[11];
    float* out = (float*)d_out;

    float*    logits = (float*)d_ws;              // 32768 floats = 131072 B
    uint32_t* w1p32  = (uint32_t*)(logits + 32768); // 64*400 u32 = 102400 B
    uint32_t* w2p    = w1p32 + 64 * 400;            // 576 u32

    pack_weights<<<103, 256, 0, stream>>>(f1w, c2w, w1p32, w2p);
    fused_cnn<<<BATCH / NS, 256, 0, stream>>>(x, c1w, c1b, c2b, w2p, w1p32,
                                              f1b, f2w, f2b, logits);
    stats_apply<<<32, 256, 0, stream>>>(logits, var, gma, bta, out);
}